// Round 2
// baseline (436.484 us; speedup 1.0000x reference)
//
#include <hip/hip_runtime.h>

// LIF activation: Vm_{t+1} = relu(x_t + (1-w_leak)*Vm_t*[Vm_t<1]), spike = [Vm>1]
// [B,T,C] = [128,1000,512] fp32.
//
// R3 -> R4: rocprof shows lif_kernel is NOT among the heavy dispatches (all
// top-5 are 1GB harness fills at ~162us) => kernel itself is <161us, and
// dur_us≈435 is ~324us of fixed restore fills + ~107us kernel. Remaining
// kernel headroom ~25us vs the 81us floor. Attack the last inefficiency:
// phase-chunked prefetch has a drain bubble per phase and 1 wave/CU can't
// cover stalls. Switch to a rolling pipeline (use buf[i], refill buf[i]
// immediately from next chunk -> constant ~20 loads in flight, no phase
// drains, no sched_barriers) at float2 granularity: 512 waves = 2 waves/CU
// so one wave's waitcnt stall is covered by the other. 512B/wave bursts,
// 2 x 10KB in flight per CU > ~9.2KB needed at ~900cyc latency.

constexpr int Bn  = 128;
constexpr int Tn  = 1000;
constexpr int Cn  = 512;
constexpr int C2  = Cn / 2;     // 256 float2 per (b,t) row
constexpr int U   = 20;         // pipeline depth (timesteps in flight)
constexpr int NCH = Tn / U;     // 50 chunks

// One LIF step for one channel; matches reference rounding exactly:
// separate mul, exact select for the keep-gate, add, relu, strict > for spike.
#define LIF_STEP(vm, oml, xin, sp)            \
    {                                          \
        float p_ = (oml) * (vm);               \
        p_ = ((vm) < 1.0f) ? p_ : 0.0f;        \
        float t_ = (xin) + p_;                 \
        (vm) = fmaxf(t_, 0.0f);                \
        (sp) = ((vm) > 1.0f) ? 1.0f : 0.0f;    \
    }

__global__ __launch_bounds__(64) void lif_kernel(const float2* __restrict__ x2,
                                                 const float*  __restrict__ w_leak,
                                                 float2* __restrict__ out2) {
    const int gid = blockIdx.x * 64 + threadIdx.x;   // 0..32767
    const int c2  = gid & (C2 - 1);                  // float2 column 0..255
    const int b   = gid >> 8;                        // batch 0..127

    const float2 wl  = reinterpret_cast<const float2*>(w_leak)[c2];
    const float omlx = 1.0f - wl.x;
    const float omly = 1.0f - wl.y;

    const size_t base = (size_t)b * Tn * C2 + c2;
    const float2* xp = x2 + base;
    float2*       op = out2 + base;

    float vmx = 0.0f, vmy = 0.0f;
    float2 buf[U];

    // fill the pipeline: timesteps 0..U-1
#pragma unroll
    for (int i = 0; i < U; ++i) buf[i] = xp[i * C2];

    // rolling main loop: consume buf[i] (chunk ch), refill from chunk ch+1.
    // Refill is issued BEFORE the step's compute so the load goes out while
    // the VALU works; it is consumed U steps (~a full chunk) later, far
    // beyond HBM latency. No phase barriers -> no drain bubbles.
    for (int ch = 0; ch < NCH - 1; ++ch) {
        const float2* xn = xp + (size_t)(ch + 1) * U * C2;
        float2*       on = op + (size_t)ch * U * C2;
#pragma unroll
        for (int i = 0; i < U; ++i) {
            float2 xv = buf[i];
            buf[i] = xn[i * C2];       // issue refill early
            float2 s;
            LIF_STEP(vmx, omlx, xv.x, s.x);
            LIF_STEP(vmy, omly, xv.y, s.y);
            on[i * C2] = s;
        }
    }

    // tail chunk: drain the pipeline, no refills
    {
        float2* on = op + (size_t)(NCH - 1) * U * C2;
#pragma unroll
        for (int i = 0; i < U; ++i) {
            float2 xv = buf[i];
            float2 s;
            LIF_STEP(vmx, omlx, xv.x, s.x);
            LIF_STEP(vmy, omly, xv.y, s.y);
            on[i * C2] = s;
        }
    }
}

extern "C" void kernel_launch(void* const* d_in, const int* in_sizes, int n_in,
                              void* d_out, int out_size, void* d_ws, size_t ws_size,
                              hipStream_t stream) {
    const float2* x      = (const float2*)d_in[0];
    const float*  w_leak = (const float*)d_in[1];
    float2*       out    = (float2*)d_out;

    // 32768 threads = 512 waves = 2 waves/CU; 64-thread blocks (1 wave each).
    lif_kernel<<<512, 64, 0, stream>>>(x, w_leak, out);
}